// Round 5
// baseline (197.093 us; speedup 1.0000x reference)
//
#include <hip/hip_runtime.h>
#include <hip/hip_bf16.h>

#define CCH 384
#define HW2 3136
#define HH 56
#define WW 56
#define QMAX 7.0f
#define SCALE_MIN 2e-16f
#define PB 49            // 64-pos blocks per image
#define YSLAB 512        // elems per (pb,c8) slab: 64 pos * 8 ci
#define YPB 24576        // 48 * 512 elems per pos-block

typedef _Float16 half8 __attribute__((ext_vector_type(8)));
typedef float f32x4 __attribute__((ext_vector_type(4)));

#define GLOAD_LDS16(g, l) __builtin_amdgcn_global_load_lds( \
    (const __attribute__((address_space(1))) void*)(g), \
    (__attribute__((address_space(3))) void*)(l), 16, 0, 0)

// ---------------- quant kernels (Brevitas per-channel symmetric int4) -------

__global__ void quant_dw(const float* __restrict__ dw, float* __restrict__ dwq) {
    int c = blockIdx.x * blockDim.x + threadIdx.x;
    if (c >= CCH) return;
    float w[9];
    float amax = 0.f;
    #pragma unroll
    for (int j = 0; j < 9; ++j) {
        w[j] = dw[c * 9 + j];
        amax = fmaxf(amax, fabsf(w[j]));
    }
    float scale = fmaxf(amax / QMAX, SCALE_MIN);
    #pragma unroll
    for (int j = 0; j < 9; ++j) {
        float q = rintf(w[j] / scale);          // round half-even = jnp.round
        q = fminf(fmaxf(q, -QMAX), QMAX);
        dwq[c * 9 + j] = q * scale;
    }
}

// one block (64 threads) per output channel; fake-quant then pack fp16 into
// MFMA A-fragment layout: wpk[(ci/32)*24 + co/16][lane][8]
__global__ void quant_pw(const float* __restrict__ pw, _Float16* __restrict__ wpk) {
    int co = blockIdx.x;
    int lane = threadIdx.x;
    float w[6];
    float amax = 0.f;
    #pragma unroll
    for (int j = 0; j < 6; ++j) {
        w[j] = pw[co * CCH + lane + j * 64];
        amax = fmaxf(amax, fabsf(w[j]));
    }
    #pragma unroll
    for (int off = 32; off >= 1; off >>= 1)
        amax = fmaxf(amax, __shfl_xor(amax, off));
    float scale = fmaxf(amax / QMAX, SCALE_MIN);
    #pragma unroll
    for (int j = 0; j < 6; ++j) {
        int ci = lane + j * 64;
        float q = rintf(w[j] / scale);
        q = fminf(fmaxf(q, -QMAX), QMAX);
        float v = q * scale;
        int kk  = ci >> 5;
        int cis = ci & 31;
        int l   = (co & 15) | ((cis >> 3) << 4);
        int idx = (kk * 24 + (co >> 4)) * 512 + l * 8 + (cis & 7);
        wpk[idx] = (_Float16)v;
    }
}

// ---------------- kernel A: depthwise 3x3 -> packed fp16 y ------------------
// Block: 256 threads = 32 global rows x 8 lane-groups; one c8 slab (8 ch).
// Thread: 7-wide row segment (w0..w0+6) x 8 channels. Per channel: 21 body
// loads + 6 exec-predicated edge loads, all independent. Vertical borders
// handled by zeroing weights; horizontal by the predicated edges.

__global__ __launch_bounds__(256) void dw_kernel(
    const float* __restrict__ x, const float* __restrict__ dwq,
    _Float16* __restrict__ ypk)
{
    // 2688 blocks = 8 XCDs * 336, chunked swizzle; wg = rb*48 + c8
    int bid = blockIdx.x;
    int wg = (bid & 7) * 336 + (bid >> 3);
    int rb = wg / 48;             // 0..55  (32-row block)
    int c8 = wg % 48;             // channel slab

    const int tid = threadIdx.x;
    const int lane8 = tid & 7;
    const int rloc = tid >> 3;
    const int r = rb * 32 + rloc;        // global row 0..1791
    const int n = r / HH, h = r - n * HH;
    const int w0 = lane8 * 7;

    const bool vt = (h > 0), vb = (h < HH - 1);
    const bool le = (lane8 == 0), re = (lane8 == 7);
    const int hm1 = vt ? h - 1 : h;      // clamped; contribution zeroed via wt
    const int hp1 = vb ? h + 1 : h;

    const float* xpl = x + (size_t)(n * CCH + c8 * 8) * HW2;
    const float* bt_m = xpl + hm1 * WW + w0;
    const float* bt_c = xpl + h   * WW + w0;
    const float* bt_p = xpl + hp1 * WW + w0;

    half8 pk[7];

    #pragma unroll
    for (int j = 0; j < 8; ++j) {
        const float* bm = bt_m + (size_t)j * HW2;
        const float* bc = bt_c + (size_t)j * HW2;
        const float* bp = bt_p + (size_t)j * HW2;

        // windows: index 0..8 = w0-1 .. w0+7
        float tm[9], md[9], bb[9];
        #pragma unroll
        for (int k = 0; k < 7; ++k) {
            tm[k + 1] = bm[k];
            md[k + 1] = bc[k];
            bb[k + 1] = bp[k];
        }
        tm[0] = le ? 0.f : bm[-1];
        md[0] = le ? 0.f : bc[-1];
        bb[0] = le ? 0.f : bp[-1];
        tm[8] = re ? 0.f : bm[7];
        md[8] = re ? 0.f : bc[7];
        bb[8] = re ? 0.f : bp[7];

        const float* wq = dwq + (c8 * 8 + j) * 9;
        float wv[9];
        #pragma unroll
        for (int k = 0; k < 9; ++k) wv[k] = wq[k];
        #pragma unroll
        for (int k = 0; k < 3; ++k) wv[k]     = vt ? wv[k]     : 0.f;
        #pragma unroll
        for (int k = 0; k < 3; ++k) wv[k + 6] = vb ? wv[k + 6] : 0.f;

        #pragma unroll
        for (int j0 = 0; j0 < 7; ++j0) {
            float a;
            a = tm[j0]     * wv[0];
            a = fmaf(tm[j0 + 1], wv[1], a);
            a = fmaf(tm[j0 + 2], wv[2], a);
            a = fmaf(md[j0],     wv[3], a);
            a = fmaf(md[j0 + 1], wv[4], a);
            a = fmaf(md[j0 + 2], wv[5], a);
            a = fmaf(bb[j0],     wv[6], a);
            a = fmaf(bb[j0 + 1], wv[7], a);
            a = fmaf(bb[j0 + 2], wv[8], a);
            pk[j0][j] = (_Float16)a;
        }
    }

    // stores: 7 contiguous 16B half8, pb-split handled per position
    const int posb = h * WW + w0;
    _Float16* yn = ypk + (size_t)n * PB * YPB + (size_t)c8 * YSLAB;
    #pragma unroll
    for (int j0 = 0; j0 < 7; ++j0) {
        const int pos = posb + j0;
        *(half8*)(yn + (size_t)(pos >> 6) * YPB + (pos & 63) * 8) = pk[j0];
    }
}

// ---------------- kernel B: pointwise GEMM (384co x 384ci x 64pos/blk) ------

__global__ __launch_bounds__(256) void pw_kernel(
    const _Float16* __restrict__ ypk, const _Float16* __restrict__ wpk,
    const float* __restrict__ bias, float* __restrict__ out)
{
    __shared__ __align__(16) _Float16 ysh[YPB];   // 48 KB

    int bid = blockIdx.x;                 // 1568 = 8 * 196
    int wg = (bid & 7) * 196 + (bid >> 3);
    int n = wg / PB, pb = wg % PB;

    const int t = threadIdx.x;
    const int lane = t & 63;
    const int g = __builtin_amdgcn_readfirstlane(t >> 6);

    // ---- stage y tile: identity copy of the packed 48KB blob ----
    const _Float16* yg = ypk + (size_t)(n * PB + pb) * YPB;
    #pragma unroll
    for (int j = 0; j < 12; ++j) {
        GLOAD_LDS16(yg + (j * 256 + t) * 8,
                    ysh + (size_t)(j * 256 + (t & 192)) * 8);
    }
    __syncthreads();

    // ---- K-loop ----
    const int lco = lane & 15;
    const int lkg = lane >> 4;
    const int cbf = g * 6;

    f32x4 acc[6][4];
    #pragma unroll
    for (int mc = 0; mc < 6; ++mc)
        #pragma unroll
        for (int np = 0; np < 4; ++np)
            acc[mc][np] = (f32x4){0.f, 0.f, 0.f, 0.f};

    for (int kk = 0; kk < 12; ++kk) {
        half8 wf[6];
        #pragma unroll
        for (int mc = 0; mc < 6; ++mc)
            wf[mc] = *(const half8*)(wpk + (size_t)(kk * 24 + cbf + mc) * 512 + lane * 8);
        half8 yf[4];
        #pragma unroll
        for (int np = 0; np < 4; ++np)
            yf[np] = *(const half8*)(ysh + kk * 2048 + lkg * 512 + (np * 16 + lco) * 8);
        #pragma unroll
        for (int mc = 0; mc < 6; ++mc)
            #pragma unroll
            for (int np = 0; np < 4; ++np)
                acc[mc][np] = __builtin_amdgcn_mfma_f32_16x16x32_f16(
                    wf[mc], yf[np], acc[mc][np], 0, 0, 0);
    }

    // ---- epilogue: bias + store ----
    float* ob = out + (size_t)n * CCH * HW2 + (size_t)pb * 64;
    #pragma unroll
    for (int mc = 0; mc < 6; ++mc) {
        #pragma unroll
        for (int r = 0; r < 4; ++r) {
            const int co = g * 96 + mc * 16 + lkg * 4 + r;
            const float bv = bias[co];
            #pragma unroll
            for (int np = 0; np < 4; ++np)
                ob[(size_t)co * HW2 + np * 16 + lco] = acc[mc][np][r] + bv;
        }
    }
}

// ---------------------------------------------------------------------------

extern "C" void kernel_launch(void* const* d_in, const int* in_sizes, int n_in,
                              void* d_out, int out_size, void* d_ws, size_t ws_size,
                              hipStream_t stream) {
    const float* x  = (const float*)d_in[0];
    const float* dw = (const float*)d_in[1];
    const float* pw = (const float*)d_in[2];
    const float* pb = (const float*)d_in[3];
    float* out = (float*)d_out;

    float*    dwq = (float*)d_ws;                         // 3456 f32
    _Float16* wpk = (_Float16*)(dwq + CCH * 9);           // 147456 fp16
    _Float16* ypk = wpk + (size_t)CCH * CCH;              // 38.5M fp16 (77 MB)

    quant_dw<<<2, 256, 0, stream>>>(dw, dwq);
    quant_pw<<<CCH, 64, 0, stream>>>(pw, wpk);

    dw_kernel<<<2688, 256, 0, stream>>>(x, dwq, ypk);
    pw_kernel<<<1568, 256, 0, stream>>>(ypk, wpk, pb, out);
}

// Round 6
// 126.009 us; speedup vs baseline: 1.5641x; 1.5641x over previous
//
#include <hip/hip_runtime.h>
#include <hip/hip_bf16.h>

#define CCH 384
#define HW2 3136
#define HH 56
#define WW 56
#define QMAX 7.0f
#define SCALE_MIN 2e-16f
#define PB 49            // 64-pos blocks per image
#define YSLAB 512        // elems per (pb,c8) slab: 64 pos * 8 ci
#define YPB 24576        // 48 * 512 elems per pos-block
#define ROWP 60          // padded LDS row stride (floats); pad [56..59] = 0
#define CHW 964          // per-channel LDS floats: 4 front pad + 16*60

typedef _Float16 half8 __attribute__((ext_vector_type(8)));
typedef float f32x4 __attribute__((ext_vector_type(4)));

#define GLOAD_LDS16(g, l) __builtin_amdgcn_global_load_lds( \
    (const __attribute__((address_space(1))) void*)(g), \
    (__attribute__((address_space(3))) void*)(l), 16, 0, 0)

// ---------------- quant kernels (Brevitas per-channel symmetric int4) -------

__global__ void quant_dw(const float* __restrict__ dw, float* __restrict__ dwq) {
    int c = blockIdx.x * blockDim.x + threadIdx.x;
    if (c >= CCH) return;
    float w[9];
    float amax = 0.f;
    #pragma unroll
    for (int j = 0; j < 9; ++j) {
        w[j] = dw[c * 9 + j];
        amax = fmaxf(amax, fabsf(w[j]));
    }
    float scale = fmaxf(amax / QMAX, SCALE_MIN);
    #pragma unroll
    for (int j = 0; j < 9; ++j) {
        float q = rintf(w[j] / scale);          // round half-even = jnp.round
        q = fminf(fmaxf(q, -QMAX), QMAX);
        dwq[c * 9 + j] = q * scale;
    }
}

// one block (64 threads) per output channel; fake-quant then pack fp16 into
// MFMA A-fragment layout: wpk[(ci/32)*24 + co/16][lane][8]
__global__ void quant_pw(const float* __restrict__ pw, _Float16* __restrict__ wpk) {
    int co = blockIdx.x;
    int lane = threadIdx.x;
    float w[6];
    float amax = 0.f;
    #pragma unroll
    for (int j = 0; j < 6; ++j) {
        w[j] = pw[co * CCH + lane + j * 64];
        amax = fmaxf(amax, fabsf(w[j]));
    }
    #pragma unroll
    for (int off = 32; off >= 1; off >>= 1)
        amax = fmaxf(amax, __shfl_xor(amax, off));
    float scale = fmaxf(amax / QMAX, SCALE_MIN);
    #pragma unroll
    for (int j = 0; j < 6; ++j) {
        int ci = lane + j * 64;
        float q = rintf(w[j] / scale);
        q = fminf(fmaxf(q, -QMAX), QMAX);
        float v = q * scale;
        int kk  = ci >> 5;
        int cis = ci & 31;
        int l   = (co & 15) | ((cis >> 3) << 4);
        int idx = (kk * 24 + (co >> 4)) * 512 + l * 8 + (cis & 7);
        wpk[idx] = (_Float16)v;
    }
}

// ---------------- kernel A (v3): LDS-staged depthwise 3x3 -------------------
// Block: 128 threads, one (n, c8 slab of 8 ch, 14-row group).
// Stage: 16 rows (incl halo) x 56 x 8ch of x via contiguous float4 loads
// (x read ONCE, wide) into LDS rows padded to 60 floats; pads + clamped edge
// rows are zeroed -> all halos are implicit zeros, compute is branch-free.
// Compute: thread = (row 0..13, wseg 0..6), 8 consecutive w x 8 channels via
// 4 aligned ds_read_b128 per (ch,row); pack half8 per position.

__global__ __launch_bounds__(128) void dw_kernel(
    const float* __restrict__ x, const float* __restrict__ dwq,
    _Float16* __restrict__ ypk)
{
    __shared__ __align__(16) float xs[8 * CHW];   // 30,848 B

    // 6144 blocks = 8 XCDs * 768, chunked swizzle; wg = (n*48 + c8)*4 + rg
    int bid = blockIdx.x;
    int wg = (bid & 7) * 768 + (bid >> 3);
    int rg = wg & 3;
    int t2 = wg >> 2;
    int c8 = t2 % 48, n = t2 / 48;
    const int h0 = rg * 14;
    const int tid = threadIdx.x;

    const float* xpl = x + ((size_t)n * CCH + (size_t)c8 * 8) * HW2;

    // ---- zero the pads ----
    {
        int s = tid >> 3, ch = tid & 7;                     // 16 rows x 8 ch
        *(f32x4*)&xs[ch * CHW + 4 + s * ROWP + 56] = (f32x4){0.f, 0.f, 0.f, 0.f};
        if (tid < 32) xs[(tid >> 2) * CHW + (tid & 3)] = 0.f;   // front pads
    }

    // ---- stage x: ch = tid>>4, 16 threads/ch, 14 contiguous float4 each ----
    {
        const int ch = tid >> 4, idx16 = tid & 15;
        const float* src = xpl + (size_t)ch * HW2;
        #pragma unroll
        for (int j = 0; j < 14; ++j) {
            const int g = j * 16 + idx16;          // 0..223 (float4 index)
            const int s = g / 14, q = g - s * 14;  // staged row, quad
            const int srow = h0 - 1 + s;
            const int crow = srow < 0 ? 0 : (srow > 55 ? 55 : srow);
            f32x4 v = *(const f32x4*)(src + crow * WW + q * 4);
            if (srow != crow) v = (f32x4){0.f, 0.f, 0.f, 0.f};
            *(f32x4*)&xs[ch * CHW + 4 + s * ROWP + q * 4] = v;
        }
    }
    __syncthreads();

    if (tid >= 98) return;                 // 14 rows x 7 wsegs = 98 tasks

    const int row  = tid / 7;
    const int wseg = tid - row * 7;
    const int w0   = wseg * 8;
    const int qlo  = (w0 - 1) >> 2;        // -1,1,3,5,7,9,11 ; front pad covers -1

    half8 pk[8];
    #pragma unroll
    for (int ch = 0; ch < 8; ++ch) {
        const float* wq = dwq + (size_t)(c8 * 8 + ch) * 9;  // uniform -> s_loads
        float wv[9];
        #pragma unroll
        for (int k = 0; k < 9; ++k) wv[k] = wq[k];

        float a[8] = {0.f,0.f,0.f,0.f,0.f,0.f,0.f,0.f};
        #pragma unroll
        for (int dr = 0; dr < 3; ++dr) {
            const int base = ch * CHW + 4 + (row + dr) * ROWP + qlo * 4;
            f32x4 q0 = *(const f32x4*)&xs[base];
            f32x4 q1 = *(const f32x4*)&xs[base + 4];
            f32x4 q2 = *(const f32x4*)&xs[base + 8];
            f32x4 q3 = *(const f32x4*)&xs[base + 12];
            float win[16] = {q0.x,q0.y,q0.z,q0.w, q1.x,q1.y,q1.z,q1.w,
                             q2.x,q2.y,q2.z,q2.w, q3.x,q3.y,q3.z,q3.w};
            // window float m corresponds to x column 4*qlo+m; out w = w0+j0
            // needs cols w0+j0-1..w0+j0+1 -> m = 3+j0 .. 5+j0 (w0-1-4*qlo == 3)
            #pragma unroll
            for (int j0 = 0; j0 < 8; ++j0) {
                float s0 = a[j0];
                s0 = fmaf(win[3 + j0], wv[dr * 3 + 0], s0);
                s0 = fmaf(win[4 + j0], wv[dr * 3 + 1], s0);
                s0 = fmaf(win[5 + j0], wv[dr * 3 + 2], s0);
                a[j0] = s0;
            }
        }
        #pragma unroll
        for (int j0 = 0; j0 < 8; ++j0) pk[j0][ch] = (_Float16)a[j0];
    }

    // ---- stores: 8 half8 (16B each), channel-packed per position ----
    const int posb = (h0 + row) * WW + w0;
    _Float16* yn = ypk + (size_t)n * PB * YPB + (size_t)c8 * YSLAB;
    #pragma unroll
    for (int j0 = 0; j0 < 8; ++j0) {
        const int pos = posb + j0;
        *(half8*)(yn + (size_t)(pos >> 6) * YPB + (pos & 63) * 8) = pk[j0];
    }
}

// ---------------- kernel B: pointwise GEMM (384co x 384ci x 64pos/blk) ------

__global__ __launch_bounds__(256) void pw_kernel(
    const _Float16* __restrict__ ypk, const _Float16* __restrict__ wpk,
    const float* __restrict__ bias, float* __restrict__ out)
{
    __shared__ __align__(16) _Float16 ysh[YPB];   // 48 KB

    int bid = blockIdx.x;                 // 1568 = 8 * 196
    int wg = (bid & 7) * 196 + (bid >> 3);
    int n = wg / PB, pb = wg % PB;

    const int t = threadIdx.x;
    const int lane = t & 63;
    const int g = __builtin_amdgcn_readfirstlane(t >> 6);

    // ---- stage y tile: identity copy of the packed 48KB blob ----
    const _Float16* yg = ypk + (size_t)(n * PB + pb) * YPB;
    #pragma unroll
    for (int j = 0; j < 12; ++j) {
        GLOAD_LDS16(yg + (j * 256 + t) * 8,
                    ysh + (size_t)(j * 256 + (t & 192)) * 8);
    }
    __syncthreads();

    // ---- K-loop ----
    const int lco = lane & 15;
    const int lkg = lane >> 4;
    const int cbf = g * 6;

    f32x4 acc[6][4];
    #pragma unroll
    for (int mc = 0; mc < 6; ++mc)
        #pragma unroll
        for (int np = 0; np < 4; ++np)
            acc[mc][np] = (f32x4){0.f, 0.f, 0.f, 0.f};

    for (int kk = 0; kk < 12; ++kk) {
        half8 wf[6];
        #pragma unroll
        for (int mc = 0; mc < 6; ++mc)
            wf[mc] = *(const half8*)(wpk + (size_t)(kk * 24 + cbf + mc) * 512 + lane * 8);
        half8 yf[4];
        #pragma unroll
        for (int np = 0; np < 4; ++np)
            yf[np] = *(const half8*)(ysh + kk * 2048 + lkg * 512 + (np * 16 + lco) * 8);
        #pragma unroll
        for (int mc = 0; mc < 6; ++mc)
            #pragma unroll
            for (int np = 0; np < 4; ++np)
                acc[mc][np] = __builtin_amdgcn_mfma_f32_16x16x32_f16(
                    wf[mc], yf[np], acc[mc][np], 0, 0, 0);
    }

    // ---- epilogue: bias + store ----
    float* ob = out + (size_t)n * CCH * HW2 + (size_t)pb * 64;
    #pragma unroll
    for (int mc = 0; mc < 6; ++mc) {
        #pragma unroll
        for (int r = 0; r < 4; ++r) {
            const int co = g * 96 + mc * 16 + lkg * 4 + r;
            const float bv = bias[co];
            #pragma unroll
            for (int np = 0; np < 4; ++np)
                ob[(size_t)co * HW2 + np * 16 + lco] = acc[mc][np][r] + bv;
        }
    }
}

// ---------------------------------------------------------------------------

extern "C" void kernel_launch(void* const* d_in, const int* in_sizes, int n_in,
                              void* d_out, int out_size, void* d_ws, size_t ws_size,
                              hipStream_t stream) {
    const float* x  = (const float*)d_in[0];
    const float* dw = (const float*)d_in[1];
    const float* pw = (const float*)d_in[2];
    const float* pb = (const float*)d_in[3];
    float* out = (float*)d_out;

    float*    dwq = (float*)d_ws;                         // 3456 f32
    _Float16* wpk = (_Float16*)(dwq + CCH * 9);           // 147456 fp16
    _Float16* ypk = wpk + (size_t)CCH * CCH;              // 38.5M fp16 (77 MB)

    quant_dw<<<2, 256, 0, stream>>>(dw, dwq);
    quant_pw<<<CCH, 64, 0, stream>>>(pw, wpk);

    dw_kernel<<<6144, 128, 0, stream>>>(x, dwq, ypk);
    pw_kernel<<<1568, 256, 0, stream>>>(ypk, wpk, pb, out);
}